// Round 3
// baseline (21142.189 us; speedup 1.0000x reference)
//
#include <hip/hip_runtime.h>
#include <hip/hip_bf16.h>
#include <stdint.h>

// Problem dims
#define NB   128
#define NT   1024
#define NV   32000
#define NE   512
#define NH   512
#define NO   5
#define N4H  2048
#define CT   128            // timesteps per chunk
#define NCHUNK (NT / CT)    // 8
#define LSTM_WG 64          // lstm blocks (8 groups x 8 wg)

typedef __attribute__((ext_vector_type(8))) short short8;   // 8 bf16 = 4 VGPR
typedef __attribute__((ext_vector_type(4))) float f32x4;    // MFMA acc

__device__ __forceinline__ float bf2f(unsigned short u){
  union { unsigned int i; float f; } x; x.i = ((unsigned int)u) << 16; return x.f;
}
__device__ __forceinline__ unsigned short f2bf(float f){
  union { __hip_bfloat16 h; unsigned short u; } x;
  x.h = __float2bfloat16(f);   // RNE
  return x.u;
}
__device__ __forceinline__ float sigm_(float x){ return 1.f / (1.f + __expf(-x)); }
__device__ __forceinline__ float tanh_(float x){
  x = fminf(fmaxf(x, -20.f), 20.f);
  float e = __expf(2.f * x);
  return (e - 1.f) / (e + 1.f);
}
__device__ __forceinline__ void gl_lds16(const void* g, void* l){
  __builtin_amdgcn_global_load_lds((const __attribute__((address_space(1))) unsigned int*)g,
                                   (__attribute__((address_space(3))) unsigned int*)l, 16, 0, 0);
}

// ---------------- K0: embed fp32 -> bf16 ----------------
__global__ void k_cvt_embed(const float* __restrict__ e, unsigned short* __restrict__ o, long n){
  long i = ((long)blockIdx.x * blockDim.x + threadIdx.x) * 4;
  long stride = (long)gridDim.x * blockDim.x * 4;
  for (; i < n; i += stride){
    float4 v = *(const float4*)(e + i);
    ushort4 r;
    r.x = f2bf(v.x); r.y = f2bf(v.y); r.z = f2bf(v.z); r.w = f2bf(v.w);
    *(ushort4*)(o + i) = r;
  }
}

// ---------------- K1: build permuted bf16 weight panels ----------------
// Permuted col space (dim-major, gate-minor): colP = D*64 + lmm*4 + gg
// where D = dimblk (j>>4), lmm = j&15, gg = gate (f,i,o,c). j = dim within gate.
// WhT[colP][k] = W_gg[k][j]        (h rows 0..511)
// WxT[colP][k] = W_gg[512+k][j]    (x rows 512..1023)
__global__ void k_prep_w(const float* __restrict__ wf, const float* __restrict__ wi,
                         const float* __restrict__ wo, const float* __restrict__ wc,
                         const float* __restrict__ bfp, const float* __restrict__ bip,
                         const float* __restrict__ bop, const float* __restrict__ bcp,
                         unsigned short* __restrict__ WhT, unsigned short* __restrict__ WxT,
                         float* __restrict__ biasP){
  int colP = blockIdx.x;                 // 0..2047
  int D = colP >> 6, rem = colP & 63;
  int lmm = rem >> 2, gg = rem & 3;
  int j = D * 16 + lmm;
  const float* w = (gg == 0) ? wf : (gg == 1) ? wi : (gg == 2) ? wo : wc;
  const float* bb = (gg == 0) ? bfp : (gg == 1) ? bip : (gg == 2) ? bop : bcp;
  for (int k = threadIdx.x; k < 512; k += blockDim.x){
    WhT[(long)colP * 512 + k] = f2bf(w[(long)k * 512 + j]);
    WxT[(long)colP * 512 + k] = f2bf(w[(long)(512 + k) * 512 + j]);
  }
  if (threadIdx.x == 0) biasP[colP] = bb[j];
}

// ---------------- K2: fused [lstm chunk lc | xproj chunk xc] ----------------
// blocks 0..63: LSTM. 8 groups (16 batch) x 8 wg; per wg 8 waves = 4 pairs.
//   pair p owns dimblk D = member*4+p (16 dims x 4 gates); waves of a pair split K
//   (kh=0: K rows 0..255, kh=1: 256..511). Weights: 128 VGPRs/wave, resident.
// blocks 64..2111: xproj GEMM tile 128x128 into xzW (chunk xc), double-buffered.
__launch_bounds__(512, 2)
__global__ void k_fused(const int* __restrict__ tok,
                        const unsigned short* __restrict__ embT,
                        const unsigned short* __restrict__ WxT,
                        const float* __restrict__ biasP,
                        const int* __restrict__ seqlen,
                        const unsigned short* __restrict__ WhT,
                        const unsigned short* __restrict__ xzR,
                        unsigned short* __restrict__ xzW,
                        unsigned short* __restrict__ hbuf,   // [2][128][512] bf16
                        float* __restrict__ hfin,            // [128][512] f32
                        int* __restrict__ flags,             // [8 groups][64] ints (32 used)
                        float* __restrict__ cbuf,            // [128][512] f32
                        int lc, int xc){
  __shared__ unsigned short S[16384];     // 32 KB (xproj A|B / C-tile; lstm RED 16 KB)
  int bid = blockIdx.x;
  int tid = threadIdx.x, w = tid >> 6, l = tid & 63;
  int lm = l & 15, lh = l >> 4;

  if (bid < LSTM_WG){
    if (lc < 0) return;
    float* RED = (float*)S;               // [pair][gate][64 lanes][4] f32
    int g = bid & 7, member = bid >> 3;
    int p = w >> 1, kh = w & 1;
    int D = member * 4 + p;               // dimblk 0..31
    int b0 = g * 16;

    int len[4];
    #pragma unroll
    for (int r = 0; r < 4; r++) len[r] = seqlen[b0 + 4 * lh + r];
    int ml = max(max(len[0], len[1]), max(len[2], len[3]));
    #pragma unroll
    for (int off = 32; off; off >>= 1) ml = max(ml, __shfl_xor(ml, off));
    int tstart = lc * CT;
    int tend = min(tstart + CT, ml);

    // stationary W_h fragments: 4 gates x 8 kfrags (this wave's K half) = 128 VGPRs
    short8 Bf[4][8];
    #pragma unroll
    for (int gg = 0; gg < 4; gg++){
      long cb = (long)(D * 64 + lm * 4 + gg) * 512 + kh * 256 + lh * 8;
      #pragma unroll
      for (int kk = 0; kk < 8; kk++)
        Bf[gg][kk] = *(const short8*)(WhT + cb + kk * 32);
    }

    long cidx[4];
    #pragma unroll
    for (int r = 0; r < 4; r++)
      cidx[r] = (long)(b0 + 4 * lh + r) * 512 + D * 16 + lm;

    float cst[4];
    #pragma unroll
    for (int r = 0; r < 4; r++)
      cst[r] = (lc == 0) ? 0.f : ((kh == 0) ? cbuf[cidx[r]] : 0.f);

    long hread_base = (long)(b0 + lm) * 512 + kh * 256 + lh * 8;   // + (t-1&1)*65536 + kk*32
    const unsigned long long* hb64 = (const unsigned long long*)hbuf;
    f32x4 zero4 = {0.f, 0.f, 0.f, 0.f};

    for (int t = tstart; t < tend; t++){
      int tl = t - tstart;
      // prefetch x-projection values (independent of h; hides under poll)
      ushort4 xv[4];
      if (kh == 0){
        #pragma unroll
        for (int r = 0; r < 4; r++)
          xv[r] = *(const ushort4*)(xzR + (long)(b0 + 4 * lh + r) * (CT * N4H)
                                        + (long)tl * N4H + D * 64 + lm * 4);
      }
      f32x4 acc[4] = {zero4, zero4, zero4, zero4};
      if (t > 0){
        // wait for all 32 pair-flags of the group to reach t
        while (true){
          int f = 0x7fffffff;
          if (l < 32)
            f = __hip_atomic_load(&flags[g * 64 + l], __ATOMIC_ACQUIRE, __HIP_MEMORY_SCOPE_AGENT);
          if (__all(f >= t)) break;
          __builtin_amdgcn_s_sleep(2);
        }
        long au = (((long)((t - 1) & 1)) * 65536 + hread_base) >> 2;   // ull index
        short8 Af[8];
        #pragma unroll
        for (int kk = 0; kk < 8; kk++){
          unsigned long long lo = __hip_atomic_load(hb64 + au + kk * 8,     __ATOMIC_RELAXED, __HIP_MEMORY_SCOPE_AGENT);
          unsigned long long hi = __hip_atomic_load(hb64 + au + kk * 8 + 1, __ATOMIC_RELAXED, __HIP_MEMORY_SCOPE_AGENT);
          struct P { unsigned long long a, b; } pr{lo, hi};
          Af[kk] = __builtin_bit_cast(short8, pr);
        }
        #pragma unroll
        for (int kk = 0; kk < 8; kk++)
          #pragma unroll
          for (int gg = 0; gg < 4; gg++)
            acc[gg] = __builtin_amdgcn_mfma_f32_16x16x32_bf16(Af[kk], Bf[gg][kk], acc[gg], 0, 0, 0);
        if (kh == 1){
          #pragma unroll
          for (int gg = 0; gg < 4; gg++)
            *(f32x4*)&RED[p * 1024 + gg * 256 + l * 4] = acc[gg];
        }
        __syncthreads();   // publish odd K-half partials (one barrier per step)
      }
      if (kh == 0){
        if (t > 0){
          #pragma unroll
          for (int gg = 0; gg < 4; gg++){
            f32x4 o = *(const f32x4*)&RED[p * 1024 + gg * 256 + l * 4];
            acc[gg][0] += o[0]; acc[gg][1] += o[1]; acc[gg][2] += o[2]; acc[gg][3] += o[3];
          }
        }
        #pragma unroll
        for (int r = 0; r < 4; r++){
          float zf = acc[0][r] + bf2f(xv[r].x);
          float zi = acc[1][r] + bf2f(xv[r].y);
          float zo = acc[2][r] + bf2f(xv[r].z);
          float zc = acc[3][r] + bf2f(xv[r].w);
          float fg = sigm_(zf), ig = sigm_(zi), og = sigm_(zo);
          float ch = tanh_(zc);
          float cn = fg * cst[r] + ig * ch;
          cst[r] = cn;
          float hn = og * tanh_(cn);
          unsigned short h16 = f2bf(hn);
          int b = b0 + 4 * lh + r;
          __hip_atomic_store(&hbuf[(long)(t & 1) * 65536 + (long)b * 512 + D * 16 + lm],
                             h16, __ATOMIC_RELAXED, __HIP_MEMORY_SCOPE_AGENT);
          if (t == len[r] - 1) hfin[cidx[r]] = hn;
        }
        // wave-level drain: all h stores of this wave at coherent point, then flag
        asm volatile("s_waitcnt vmcnt(0)" ::: "memory");
        if (l == 0)
          __hip_atomic_store(&flags[g * 64 + member * 4 + p], t + 1,
                             __ATOMIC_RELEASE, __HIP_MEMORY_SCOPE_AGENT);
      }
    }
    if (kh == 0){
      #pragma unroll
      for (int r = 0; r < 4; r++) cbuf[cidx[r]] = cst[r];
    }
    return;
  }

  // ---------------- xproj: 128x128 tile of chunk xc ----------------
  if (xc < 0) return;
  int bx = bid - LSTM_WG;                  // 0..2047
  int tn = bx & 15, tm = bx >> 4;
  int m0 = tm * 128, n0 = tn * 128;
  unsigned short* Ash = S;                 // [128][64]
  unsigned short* Bsh = S + 8192;          // [128][64]

  long srcA[2], srcB[2];
  #pragma unroll
  for (int q = 0; q < 2; q++){
    int li = q * 512 + tid;
    int row = li >> 3, c8 = (li & 7) * 8;
    int m = m0 + row;
    int b = m >> 7, tl = m & (CT - 1);
    int tkn = tok[b * NT + xc * CT + tl];
    srcA[q] = (long)tkn * 512 + c8;
    srcB[q] = (long)(n0 + row) * 512 + c8;
  }
  f32x4 acc[4][2];
  f32x4 z4 = {0.f, 0.f, 0.f, 0.f};
  #pragma unroll
  for (int mt = 0; mt < 4; mt++){ acc[mt][0] = z4; acc[mt][1] = z4; }
  int wm = w >> 2, wn = w & 3;

  for (int kt = 0; kt < 8; kt++){
    #pragma unroll
    for (int q = 0; q < 2; q++){
      gl_lds16(embT + srcA[q] + kt * 64, Ash + (q * 512 + w * 64) * 8);
      gl_lds16(WxT  + srcB[q] + kt * 64, Bsh + (q * 512 + w * 64) * 8);
    }
    __syncthreads();
    #pragma unroll
    for (int kk = 0; kk < 2; kk++){
      short8 a[4], bfr[2];
      #pragma unroll
      for (int mt = 0; mt < 4; mt++)
        a[mt] = *(const short8*)(Ash + (64 * wm + 16 * mt + lm) * 64 + kk * 32 + lh * 8);
      #pragma unroll
      for (int nt = 0; nt < 2; nt++)
        bfr[nt] = *(const short8*)(Bsh + (32 * wn + 16 * nt + lm) * 64 + kk * 32 + lh * 8);
      #pragma unroll
      for (int mt = 0; mt < 4; mt++)
        #pragma unroll
        for (int nt = 0; nt < 2; nt++)
          acc[mt][nt] = __builtin_amdgcn_mfma_f32_16x16x32_bf16(a[mt], bfr[nt], acc[mt][nt], 0, 0, 0);
    }
    __syncthreads();
  }
  // epilogue through LDS C-tile
  #pragma unroll
  for (int mt = 0; mt < 4; mt++)
    #pragma unroll
    for (int nt = 0; nt < 2; nt++)
      #pragma unroll
      for (int r = 0; r < 4; r++){
        int mm = 64 * wm + 16 * mt + 4 * lh + r;
        int nn = 32 * wn + 16 * nt + lm;
        S[mm * 128 + nn] = f2bf(acc[mt][nt][r] + biasP[n0 + nn]);
      }
  __syncthreads();
  #pragma unroll
  for (int it = 0; it < 4; it++){
    int i = it * 512 + tid;                // 0..2047
    int row = i >> 4, ch = i & 15;
    *reinterpret_cast<uint4*>(xzW + (long)(m0 + row) * N4H + n0 + ch * 8) =
        *reinterpret_cast<const uint4*>(S + row * 128 + ch * 8);
  }
}

// ---------------- K4: final FC [128,512]@[512,5] fp32 ----------------
__global__ void k_fc(const float* __restrict__ hfin, const float* __restrict__ fcw,
                     const float* __restrict__ fcb, float* __restrict__ out){
  int b = blockIdx.x;
  int l = threadIdx.x;                     // 64 threads = 1 wave
  const float* h = hfin + (long)b * 512;
  float a[5] = {0.f, 0.f, 0.f, 0.f, 0.f};
  for (int k = l; k < 512; k += 64){
    float hv = h[k];
    #pragma unroll
    for (int o = 0; o < 5; o++) a[o] += hv * fcw[k * 5 + o];
  }
  #pragma unroll
  for (int o = 0; o < 5; o++){
    float v = a[o];
    #pragma unroll
    for (int off = 32; off; off >>= 1) v += __shfl_xor(v, off);
    if (l == 0) out[b * 5 + o] = v + fcb[o];
  }
}

extern "C" void kernel_launch(void* const* d_in, const int* in_sizes, int n_in,
                              void* d_out, int out_size, void* d_ws, size_t ws_size,
                              hipStream_t stream) {
  const int*   inputs = (const int*)  d_in[0];
  const int*   seqlen = (const int*)  d_in[1];
  const float* embed  = (const float*)d_in[2];
  const float* wf  = (const float*)d_in[3];
  const float* bfp = (const float*)d_in[4];
  const float* wi  = (const float*)d_in[5];
  const float* bip = (const float*)d_in[6];
  const float* wo  = (const float*)d_in[7];
  const float* bop = (const float*)d_in[8];
  const float* wc  = (const float*)d_in[9];
  const float* bcp = (const float*)d_in[10];
  const float* fcw = (const float*)d_in[11];
  const float* fcb = (const float*)d_in[12];
  float* out = (float*)d_out;

  size_t SZ_XZ   = (size_t)NB * CT * N4H * 2;      // 64 MB per buffer
  size_t SZ_EMBT = (size_t)NV * NE * 2;            // 31.25 MB
  size_t SZ_W    = (size_t)N4H * 512 * 2;          // 2 MB
  size_t SZ_BIAS = (size_t)N4H * 4;                // 8 KB
  size_t SZ_HBUF = (size_t)2 * NB * NH * 2;        // 256 KB
  size_t SZ_F32B = (size_t)NB * NH * 4;            // 256 KB (cbuf / hfin)
  size_t SZ_FLAG = 4096;
  size_t fixed = SZ_EMBT + 2 * SZ_W + SZ_BIAS + SZ_HBUF + 2 * SZ_F32B + SZ_FLAG;
  bool dbuf = (ws_size >= 2 * SZ_XZ + fixed);
  int nxz = dbuf ? 2 : 1;
  if (ws_size < SZ_XZ + fixed){
    hipMemsetAsync(d_out, 0, (size_t)out_size * 4, stream);   // diagnostic signature
    return;
  }

  char* ws = (char*)d_ws;
  unsigned short* xzb[2];
  xzb[0] = (unsigned short*)ws;
  xzb[1] = dbuf ? (unsigned short*)(ws + SZ_XZ) : xzb[0];
  char* base = ws + (size_t)nxz * SZ_XZ;
  unsigned short* embT  = (unsigned short*)(base);
  unsigned short* WxT   = (unsigned short*)(base + SZ_EMBT);
  unsigned short* WhT   = (unsigned short*)(base + SZ_EMBT + SZ_W);
  float*          biasP = (float*)        (base + SZ_EMBT + 2 * SZ_W);
  unsigned short* hbuf  = (unsigned short*)(base + SZ_EMBT + 2 * SZ_W + SZ_BIAS);
  float*          cbuf  = (float*)        (base + SZ_EMBT + 2 * SZ_W + SZ_BIAS + SZ_HBUF);
  float*          hfin  = (float*)        (base + SZ_EMBT + 2 * SZ_W + SZ_BIAS + SZ_HBUF + SZ_F32B);
  int*            flags = (int*)          (base + SZ_EMBT + 2 * SZ_W + SZ_BIAS + SZ_HBUF + 2 * SZ_F32B);

  hipMemsetAsync(flags, 0, SZ_FLAG, stream);
  k_cvt_embed<<<2048, 256, 0, stream>>>(embed, embT, (long)NV * NE);
  k_prep_w<<<2048, 256, 0, stream>>>(wf, wi, wo, wc, bfp, bip, bop, bcp, WhT, WxT, biasP);

  if (dbuf){
    for (int c = 0; c <= NCHUNK; c++){
      int xc = (c < NCHUNK) ? c : -1;
      int lcc = c - 1;
      const unsigned short* xr = xzb[(c + 1) & 1];   // = (c-1)&1
      unsigned short* xw = xzb[c & 1];
      k_fused<<<LSTM_WG + 2048, 512, 0, stream>>>(inputs, embT, WxT, biasP, seqlen, WhT,
                                                  xr, xw, hbuf, hfin, flags, cbuf, lcc, xc);
    }
  } else {
    for (int c = 0; c < NCHUNK; c++){
      k_fused<<<LSTM_WG + 2048, 512, 0, stream>>>(inputs, embT, WxT, biasP, seqlen, WhT,
                                                  xzb[0], xzb[0], hbuf, hfin, flags, cbuf, -1, c);
      k_fused<<<LSTM_WG + 2048, 512, 0, stream>>>(inputs, embT, WxT, biasP, seqlen, WhT,
                                                  xzb[0], xzb[0], hbuf, hfin, flags, cbuf, c, -1);
    }
  }
  k_fc<<<128, 64, 0, stream>>>(hfin, fcw, fcb, out);
}

// Round 4
// 8173.615 us; speedup vs baseline: 2.5866x; 2.5866x over previous
//
#include <hip/hip_runtime.h>
#include <hip/hip_bf16.h>
#include <stdint.h>

// Problem dims
#define NB   128
#define NT   1024
#define NV   32000
#define NE   512
#define NH   512
#define NO   5
#define N4H  2048
#define CT   128            // timesteps per chunk
#define NCHUNK (NT / CT)    // 8

typedef __attribute__((ext_vector_type(8))) short short8;   // 8 bf16 = 4 VGPR
typedef __attribute__((ext_vector_type(4))) float f32x4;    // MFMA acc

__device__ __forceinline__ float bf2f(unsigned short u){
  union { unsigned int i; float f; } x; x.i = ((unsigned int)u) << 16; return x.f;
}
__device__ __forceinline__ unsigned short f2bf(float f){
  union { __hip_bfloat16 h; unsigned short u; } x;
  x.h = __float2bfloat16(f);   // RNE
  return x.u;
}
__device__ __forceinline__ float sigm_(float x){ return 1.f / (1.f + __expf(-x)); }
__device__ __forceinline__ float tanh_(float x){
  x = fminf(fmaxf(x, -20.f), 20.f);
  float e = __expf(2.f * x);
  return (e - 1.f) / (e + 1.f);
}
__device__ __forceinline__ void gl_lds16(const void* g, void* l){
  __builtin_amdgcn_global_load_lds((const __attribute__((address_space(1))) unsigned int*)g,
                                   (__attribute__((address_space(3))) unsigned int*)l, 16, 0, 0);
}

// ---------------- K0: embed fp32 -> bf16 ----------------
__global__ void k_cvt_embed(const float* __restrict__ e, unsigned short* __restrict__ o, long n){
  long i = ((long)blockIdx.x * blockDim.x + threadIdx.x) * 4;
  long stride = (long)gridDim.x * blockDim.x * 4;
  for (; i < n; i += stride){
    float4 v = *(const float4*)(e + i);
    ushort4 r;
    r.x = f2bf(v.x); r.y = f2bf(v.y); r.z = f2bf(v.z); r.w = f2bf(v.w);
    *(ushort4*)(o + i) = r;
  }
}

// ---------------- K1: build permuted bf16 weight panels ----------------
// Permuted col space (dim-major, gate-minor): colP = D*64 + lmm*4 + gg
// where D = dimblk (j>>4), lmm = j&15, gg = gate (f,i,o,c). j = dim within gate.
// WhT[colP][k] = W_gg[k][j]        (h rows 0..511)
// WxT[colP][k] = W_gg[512+k][j]    (x rows 512..1023)
__global__ void k_prep_w(const float* __restrict__ wf, const float* __restrict__ wi,
                         const float* __restrict__ wo, const float* __restrict__ wc,
                         const float* __restrict__ bfp, const float* __restrict__ bip,
                         const float* __restrict__ bop, const float* __restrict__ bcp,
                         unsigned short* __restrict__ WhT, unsigned short* __restrict__ WxT,
                         float* __restrict__ biasP){
  int colP = blockIdx.x;                 // 0..2047
  int D = colP >> 6, rem = colP & 63;
  int lmm = rem >> 2, gg = rem & 3;
  int j = D * 16 + lmm;
  const float* w = (gg == 0) ? wf : (gg == 1) ? wi : (gg == 2) ? wo : wc;
  const float* bb = (gg == 0) ? bfp : (gg == 1) ? bip : (gg == 2) ? bop : bcp;
  for (int k = threadIdx.x; k < 512; k += blockDim.x){
    WhT[(long)colP * 512 + k] = f2bf(w[(long)k * 512 + j]);
    WxT[(long)colP * 512 + k] = f2bf(w[(long)(512 + k) * 512 + j]);
  }
  if (threadIdx.x == 0) biasP[colP] = bb[j];
}

// ---------------- K2: input projection GEMM for one time-chunk (R2-proven) ----------------
__launch_bounds__(256, 2)
__global__ void k_xproj(const int* __restrict__ tok, const unsigned short* __restrict__ embT,
                        const unsigned short* __restrict__ WxT, const float* __restrict__ biasP,
                        unsigned short* __restrict__ xz, int c){
  __shared__ unsigned short S[16384];           // 32 KB: A(16K) + B(16K), reused as C-tile
  unsigned short* Ash = S;
  unsigned short* Bsh = S + 8192;
  int bx = blockIdx.x;
  int tn = bx & 15, tm = bx >> 4;               // 16 n-tiles, 128 m-tiles
  int m0 = tm * 128, n0 = tn * 128;
  int tid = threadIdx.x, w = tid >> 6, l = tid & 63;

  long srcA[4], srcB[4];
  #pragma unroll
  for (int i = 0; i < 4; i++){
    int rr = 32 * w + 8 * i + (l >> 3);
    int r_glob = m0 + rr;
    int b  = r_glob >> 7;                       // / CT
    int tl = r_glob & (CT - 1);
    int t = tok[b * NT + c * CT + tl];
    srcA[i] = (long)t * 512 + (l & 7) * 8;
    srcB[i] = (long)(n0 + rr) * 512 + (l & 7) * 8;
  }
  f32x4 acc[4][4];
  f32x4 z4 = {0.f, 0.f, 0.f, 0.f};
  #pragma unroll
  for (int mt = 0; mt < 4; mt++)
    #pragma unroll
    for (int nt = 0; nt < 4; nt++) acc[mt][nt] = z4;

  int wm = w >> 1, wn = w & 1;
  for (int kt = 0; kt < 8; kt++){
    #pragma unroll
    for (int i = 0; i < 4; i++){
      gl_lds16(embT + srcA[i] + kt * 64, Ash + (32 * w + 8 * i) * 64);
      gl_lds16(WxT  + srcB[i] + kt * 64, Bsh + (32 * w + 8 * i) * 64);
    }
    __syncthreads();
    #pragma unroll
    for (int kk = 0; kk < 2; kk++){
      short8 a[4], b[4];
      #pragma unroll
      for (int mt = 0; mt < 4; mt++)
        a[mt] = *(const short8*)(Ash + (64 * wm + 16 * mt + (l & 15)) * 64 + kk * 32 + (l >> 4) * 8);
      #pragma unroll
      for (int nt = 0; nt < 4; nt++)
        b[nt] = *(const short8*)(Bsh + (64 * wn + 16 * nt + (l & 15)) * 64 + kk * 32 + (l >> 4) * 8);
      #pragma unroll
      for (int mt = 0; mt < 4; mt++)
        #pragma unroll
        for (int nt = 0; nt < 4; nt++)
          acc[mt][nt] = __builtin_amdgcn_mfma_f32_16x16x32_bf16(a[mt], b[nt], acc[mt][nt], 0, 0, 0);
    }
    __syncthreads();
  }
  #pragma unroll
  for (int mt = 0; mt < 4; mt++)
    #pragma unroll
    for (int nt = 0; nt < 4; nt++)
      #pragma unroll
      for (int r = 0; r < 4; r++){
        int mm = 64 * wm + 16 * mt + 4 * (l >> 4) + r;
        int nn = 64 * wn + 16 * nt + (l & 15);
        float z = acc[mt][nt][r] + biasP[n0 + nn];
        S[mm * 128 + nn] = f2bf(z);
      }
  __syncthreads();
  #pragma unroll
  for (int it = 0; it < 8; it++){
    int i = it * 256 + tid;                 // 0..2047
    int row = i >> 4, ch = i & 15;
    *reinterpret_cast<uint4*>(xz + (long)(m0 + row) * 2048 + n0 + ch * 8) =
        *reinterpret_cast<const uint4*>(S + row * 128 + ch * 8);
  }
}

// ---------------- K3: recurrent LSTM, one time-chunk ----------------
// 64 blocks x 512 thr. 8 groups (16 batch) x 8 members; per block 8 waves = 4 pairs.
// Pair p owns dimblk D = member*4+p (16 dims x 4 gates); waves of a pair split K
// (kh=0: k 0..255, kh=1: 256..511) -> 128 VGPRs of stationary weights per wave.
// All-relaxed agent protocol: h stores (LLC write-through) -> vmcnt drain ->
// relaxed per-pair flag; readers poll 32 flags relaxed, h loads LLC-direct.
__launch_bounds__(512, 1)
__global__ void k_lstm(const int* __restrict__ seqlen,
                       const unsigned short* __restrict__ WhT,
                       const unsigned short* __restrict__ xz,   // chunk-local [128][CT][2048]
                       unsigned short* __restrict__ hbuf,       // [2][128][512] bf16
                       float* __restrict__ hfin,                // [128][512] f32
                       int* __restrict__ flags,                 // [8 groups][64] ints (32 used)
                       float* __restrict__ cbuf,                // [128][512] f32
                       int lc){
  __shared__ float RED[4096];              // [pair][gate][64 lanes][4] f32 = 16 KB
  int bid = blockIdx.x;
  int g = bid & 7, member = bid >> 3;
  int tid = threadIdx.x, w = tid >> 6, l = tid & 63;
  int lm = l & 15, lh = l >> 4;
  int p = w >> 1, kh = w & 1;
  int D = member * 4 + p;                  // dimblk 0..31
  int b0 = g * 16;

  int len[4];
  #pragma unroll
  for (int r = 0; r < 4; r++) len[r] = seqlen[b0 + 4 * lh + r];
  int ml = max(max(len[0], len[1]), max(len[2], len[3]));
  #pragma unroll
  for (int off = 32; off; off >>= 1) ml = max(ml, __shfl_xor(ml, off));
  int tstart = lc * CT;
  int tend = min(tstart + CT, ml);
  if (tend <= tstart) return;              // group finished in earlier chunk (uniform per block)

  // stationary W_h fragments: 4 gates x 8 k-frags (this wave's K half) = 128 VGPRs
  short8 Bf[4][8];
  #pragma unroll
  for (int gg = 0; gg < 4; gg++){
    long cb = (long)(D * 64 + lm * 4 + gg) * 512 + kh * 256 + lh * 8;
    #pragma unroll
    for (int kk = 0; kk < 8; kk++)
      Bf[gg][kk] = *(const short8*)(WhT + cb + kk * 32);
  }

  long cidx[4];
  #pragma unroll
  for (int r = 0; r < 4; r++)
    cidx[r] = (long)(b0 + 4 * lh + r) * 512 + D * 16 + lm;

  float cst[4];
  #pragma unroll
  for (int r = 0; r < 4; r++)
    cst[r] = (lc == 0) ? 0.f : ((kh == 0) ? cbuf[cidx[r]] : 0.f);

  long hread_base = (long)(b0 + lm) * 512 + kh * 256 + lh * 8;   // + par*65536 + kk*32
  const unsigned long long* hb64 = (const unsigned long long*)hbuf;
  const int* fl = flags + g * 64 + (l & 31);
  f32x4 zero4 = {0.f, 0.f, 0.f, 0.f};

  for (int t = tstart; t < tend; t++){
    int tl = t - tstart;
    // prefetch x-projection values (plain cached loads; independent of h)
    ushort4 xv[4];
    if (kh == 0){
      #pragma unroll
      for (int r = 0; r < 4; r++)
        xv[r] = *(const ushort4*)(xz + (long)(b0 + 4 * lh + r) * (CT * N4H)
                                      + (long)tl * N4H + D * 64 + lm * 4);
    }
    f32x4 acc[4] = {zero4, zero4, zero4, zero4};
    if (t > 0){
      // relaxed poll on the group's 32 pair-flags (all lanes participate)
      while (true){
        int f = __hip_atomic_load(fl, __ATOMIC_RELAXED, __HIP_MEMORY_SCOPE_AGENT);
        if (__all(f >= t)) break;
        __builtin_amdgcn_s_sleep(1);
      }
      asm volatile("" ::: "memory");       // pin compiler ordering (no HW fence needed: sc1 loads)
      long au = (((long)((t - 1) & 1)) * 65536 + hread_base) >> 2;   // ull index
      short8 Af[8];
      #pragma unroll
      for (int kk = 0; kk < 8; kk++){
        unsigned long long lo = __hip_atomic_load(hb64 + au + kk * 8,     __ATOMIC_RELAXED, __HIP_MEMORY_SCOPE_AGENT);
        unsigned long long hi = __hip_atomic_load(hb64 + au + kk * 8 + 1, __ATOMIC_RELAXED, __HIP_MEMORY_SCOPE_AGENT);
        struct P { unsigned long long a, b; } pr{lo, hi};
        Af[kk] = __builtin_bit_cast(short8, pr);
      }
      #pragma unroll
      for (int kk = 0; kk < 8; kk++)
        #pragma unroll
        for (int gg = 0; gg < 4; gg++)
          acc[gg] = __builtin_amdgcn_mfma_f32_16x16x32_bf16(Af[kk], Bf[gg][kk], acc[gg], 0, 0, 0);
      if (kh == 1){
        #pragma unroll
        for (int gg = 0; gg < 4; gg++)
          *(f32x4*)&RED[p * 1024 + gg * 256 + l * 4] = acc[gg];
      }
      __syncthreads();                     // publish odd K-half partials
    }
    if (kh == 0){
      if (t > 0){
        #pragma unroll
        for (int gg = 0; gg < 4; gg++){
          f32x4 o = *(const f32x4*)&RED[p * 1024 + gg * 256 + l * 4];
          acc[gg][0] += o[0]; acc[gg][1] += o[1]; acc[gg][2] += o[2]; acc[gg][3] += o[3];
        }
      }
      #pragma unroll
      for (int r = 0; r < 4; r++){
        float zf = acc[0][r] + bf2f(xv[r].x);
        float zi = acc[1][r] + bf2f(xv[r].y);
        float zo = acc[2][r] + bf2f(xv[r].z);
        float zc = acc[3][r] + bf2f(xv[r].w);
        float fg = sigm_(zf), ig = sigm_(zi), og = sigm_(zo);
        float ch = tanh_(zc);
        float cn = fg * cst[r] + ig * ch;
        cst[r] = cn;
        float hn = og * tanh_(cn);
        unsigned short h16 = f2bf(hn);
        int b = b0 + 4 * lh + r;
        __hip_atomic_store(&hbuf[(long)(t & 1) * 65536 + (long)b * 512 + D * 16 + lm],
                           h16, __ATOMIC_RELAXED, __HIP_MEMORY_SCOPE_AGENT);
        if (t == len[r] - 1) hfin[cidx[r]] = hn;
      }
      // drain this wave's h stores to the coherent point, then publish flag (relaxed)
      asm volatile("s_waitcnt vmcnt(0)" ::: "memory");
      if (l == 0)
        __hip_atomic_store(&flags[g * 64 + member * 4 + p], t + 1,
                           __ATOMIC_RELAXED, __HIP_MEMORY_SCOPE_AGENT);
    }
  }
  if (kh == 0){
    #pragma unroll
    for (int r = 0; r < 4; r++) cbuf[cidx[r]] = cst[r];
  }
}

// ---------------- K4: final FC [128,512]@[512,5] fp32 ----------------
__global__ void k_fc(const float* __restrict__ hfin, const float* __restrict__ fcw,
                     const float* __restrict__ fcb, float* __restrict__ out){
  int b = blockIdx.x;
  int l = threadIdx.x;                     // 64 threads = 1 wave
  const float* h = hfin + (long)b * 512;
  float a[5] = {0.f, 0.f, 0.f, 0.f, 0.f};
  for (int k = l; k < 512; k += 64){
    float hv = h[k];
    #pragma unroll
    for (int o = 0; o < 5; o++) a[o] += hv * fcw[k * 5 + o];
  }
  #pragma unroll
  for (int o = 0; o < 5; o++){
    float v = a[o];
    #pragma unroll
    for (int off = 32; off; off >>= 1) v += __shfl_xor(v, off);
    if (l == 0) out[b * 5 + o] = v + fcb[o];
  }
}

extern "C" void kernel_launch(void* const* d_in, const int* in_sizes, int n_in,
                              void* d_out, int out_size, void* d_ws, size_t ws_size,
                              hipStream_t stream) {
  const int*   inputs = (const int*)  d_in[0];
  const int*   seqlen = (const int*)  d_in[1];
  const float* embed  = (const float*)d_in[2];
  const float* wf  = (const float*)d_in[3];
  const float* bfp = (const float*)d_in[4];
  const float* wi  = (const float*)d_in[5];
  const float* bip = (const float*)d_in[6];
  const float* wo  = (const float*)d_in[7];
  const float* bop = (const float*)d_in[8];
  const float* wc  = (const float*)d_in[9];
  const float* bcp = (const float*)d_in[10];
  const float* fcw = (const float*)d_in[11];
  const float* fcb = (const float*)d_in[12];
  float* out = (float*)d_out;

  // workspace layout (bytes)
  size_t SZ_XZ   = (size_t)NB * CT * N4H * 2;      // 64 MB (one time-chunk)
  size_t SZ_EMBT = (size_t)NV * NE * 2;            // 31.25 MB
  size_t SZ_W    = (size_t)N4H * 512 * 2;          // 2 MB
  size_t SZ_BIAS = (size_t)N4H * 4;                // 8 KB
  size_t SZ_HBUF = (size_t)2 * NB * NH * 2;        // 256 KB
  size_t SZ_F32B = (size_t)NB * NH * 4;            // 256 KB (cbuf / hfin)
  size_t SZ_FLAG = 4096;
  size_t need = SZ_XZ + SZ_EMBT + 2 * SZ_W + SZ_BIAS + SZ_HBUF + 2 * SZ_F32B + SZ_FLAG;
  if (ws_size < need){
    hipMemsetAsync(d_out, 0, (size_t)out_size * 4, stream);   // diagnostic signature
    return;
  }

  char* ws = (char*)d_ws;
  unsigned short* xz    = (unsigned short*)(ws);
  unsigned short* embT  = (unsigned short*)(ws + SZ_XZ);
  unsigned short* WxT   = (unsigned short*)(ws + SZ_XZ + SZ_EMBT);
  unsigned short* WhT   = (unsigned short*)(ws + SZ_XZ + SZ_EMBT + SZ_W);
  float*          biasP = (float*)        (ws + SZ_XZ + SZ_EMBT + 2 * SZ_W);
  unsigned short* hbuf  = (unsigned short*)(ws + SZ_XZ + SZ_EMBT + 2 * SZ_W + SZ_BIAS);
  float*          cbuf  = (float*)        (ws + SZ_XZ + SZ_EMBT + 2 * SZ_W + SZ_BIAS + SZ_HBUF);
  float*          hfin  = (float*)        (ws + SZ_XZ + SZ_EMBT + 2 * SZ_W + SZ_BIAS + SZ_HBUF + SZ_F32B);
  int*            flags = (int*)          (ws + SZ_XZ + SZ_EMBT + 2 * SZ_W + SZ_BIAS + SZ_HBUF + 2 * SZ_F32B);

  hipMemsetAsync(flags, 0, SZ_FLAG, stream);
  k_cvt_embed<<<2048, 256, 0, stream>>>(embed, embT, (long)NV * NE);
  k_prep_w<<<2048, 256, 0, stream>>>(wf, wi, wo, wc, bfp, bip, bop, bcp, WhT, WxT, biasP);

  for (int c = 0; c < NCHUNK; c++){
    k_xproj<<<2048, 256, 0, stream>>>(inputs, embT, WxT, biasP, xz, c);
    k_lstm<<<64, 512, 0, stream>>>(seqlen, WhT, xz, hbuf, hfin, flags, cbuf, c);
  }
  k_fc<<<128, 64, 0, stream>>>(hfin, fcw, fcb, out);
}

// Round 6
// 6449.438 us; speedup vs baseline: 3.2781x; 1.2673x over previous
//
#include <hip/hip_runtime.h>
#include <hip/hip_bf16.h>
#include <stdint.h>

// Problem dims
#define NB   128
#define NT   1024
#define NV   32000
#define NE   512
#define NH   512
#define NO   5
#define N4H  2048
#define CT   128            // timesteps per chunk
#define NCHUNK (NT / CT)    // 8
#define SPIN_CAP 200000     // failsafe: degrade to wrong-answer instead of container hang

typedef __attribute__((ext_vector_type(8))) short short8;   // 8 bf16 = 4 VGPR
typedef __attribute__((ext_vector_type(4))) float f32x4;    // MFMA acc
typedef __attribute__((ext_vector_type(4))) int   i32x4a;   // 4 AGPRs under "a"

__device__ __forceinline__ float bf2f(unsigned short u){
  union { unsigned int i; float f; } x; x.i = ((unsigned int)u) << 16; return x.f;
}
__device__ __forceinline__ unsigned short f2bf(float f){
  union { __hip_bfloat16 h; unsigned short u; } x;
  x.h = __float2bfloat16(f);   // RNE
  return x.u;
}
__device__ __forceinline__ float sigm_(float x){ return 1.f / (1.f + __expf(-x)); }
__device__ __forceinline__ float tanh_(float x){
  x = fminf(fmaxf(x, -20.f), 20.f);
  float e = __expf(2.f * x);
  return (e - 1.f) / (e + 1.f);
}
__device__ __forceinline__ void gl_lds16(const void* g, void* l){
  __builtin_amdgcn_global_load_lds((const __attribute__((address_space(1))) unsigned int*)g,
                                   (__attribute__((address_space(3))) unsigned int*)l, 16, 0, 0);
}
// load 16B straight into 4 AGPRs (pinned weight storage; allocator cannot remat)
__device__ __forceinline__ i32x4a agpr_load16(const unsigned short* p){
  i32x4a r;
  asm volatile("global_load_dwordx4 %0, %1, off" : "=a"(r) : "v"(p));
  return r;
}
// acc(C in VGPR) += A(VGPR) * B(AGPR)
__device__ __forceinline__ void mfma_a(f32x4& acc, short8 a, i32x4a b){
  asm volatile("v_mfma_f32_16x16x32_bf16 %0, %1, %2, %0" : "+v"(acc) : "v"(a), "a"(b));
}

// ---------------- K0: embed fp32 -> bf16 ----------------
__global__ void k_cvt_embed(const float* __restrict__ e, unsigned short* __restrict__ o, long n){
  long i = ((long)blockIdx.x * blockDim.x + threadIdx.x) * 4;
  long stride = (long)gridDim.x * blockDim.x * 4;
  for (; i < n; i += stride){
    float4 v = *(const float4*)(e + i);
    ushort4 r;
    r.x = f2bf(v.x); r.y = f2bf(v.y); r.z = f2bf(v.z); r.w = f2bf(v.w);
    *(ushort4*)(o + i) = r;
  }
}

// ---------------- K1: build permuted bf16 weight panels ----------------
// Permuted col space (dim-major, gate-minor): colP = D*64 + lmm*4 + gg
// where D = dimblk (j>>4), lmm = j&15, gg = gate (f,i,o,c). j = dim within gate.
// WhT[colP][k] = W_gg[k][j]        (h rows 0..511)
// WxT[colP][k] = W_gg[512+k][j]    (x rows 512..1023)
__global__ void k_prep_w(const float* __restrict__ wf, const float* __restrict__ wi,
                         const float* __restrict__ wo, const float* __restrict__ wc,
                         const float* __restrict__ bfp, const float* __restrict__ bip,
                         const float* __restrict__ bop, const float* __restrict__ bcp,
                         unsigned short* __restrict__ WhT, unsigned short* __restrict__ WxT,
                         float* __restrict__ biasP){
  int colP = blockIdx.x;                 // 0..2047
  int D = colP >> 6, rem = colP & 63;
  int lmm = rem >> 2, gg = rem & 3;
  int j = D * 16 + lmm;
  const float* w = (gg == 0) ? wf : (gg == 1) ? wi : (gg == 2) ? wo : wc;
  const float* bb = (gg == 0) ? bfp : (gg == 1) ? bip : (gg == 2) ? bop : bcp;
  for (int k = threadIdx.x; k < 512; k += blockDim.x){
    WhT[(long)colP * 512 + k] = f2bf(w[(long)k * 512 + j]);
    WxT[(long)colP * 512 + k] = f2bf(w[(long)(512 + k) * 512 + j]);
  }
  if (threadIdx.x == 0) biasP[colP] = bb[j];
}

// ---------------- K2: input projection GEMM for one time-chunk (R2-proven) ----------------
__launch_bounds__(256, 2)
__global__ void k_xproj(const int* __restrict__ tok, const unsigned short* __restrict__ embT,
                        const unsigned short* __restrict__ WxT, const float* __restrict__ biasP,
                        unsigned short* __restrict__ xz, int c){
  __shared__ unsigned short S[16384];           // 32 KB: A(16K) + B(16K), reused as C-tile
  unsigned short* Ash = S;
  unsigned short* Bsh = S + 8192;
  int bx = blockIdx.x;
  int tn = bx & 15, tm = bx >> 4;               // 16 n-tiles, 128 m-tiles
  int m0 = tm * 128, n0 = tn * 128;
  int tid = threadIdx.x, w = tid >> 6, l = tid & 63;

  long srcA[4], srcB[4];
  #pragma unroll
  for (int i = 0; i < 4; i++){
    int rr = 32 * w + 8 * i + (l >> 3);
    int r_glob = m0 + rr;
    int b  = r_glob >> 7;                       // / CT
    int tl = r_glob & (CT - 1);
    int t = tok[b * NT + c * CT + tl];
    srcA[i] = (long)t * 512 + (l & 7) * 8;
    srcB[i] = (long)(n0 + rr) * 512 + (l & 7) * 8;
  }
  f32x4 acc[4][4];
  f32x4 z4 = {0.f, 0.f, 0.f, 0.f};
  #pragma unroll
  for (int mt = 0; mt < 4; mt++)
    #pragma unroll
    for (int nt = 0; nt < 4; nt++) acc[mt][nt] = z4;

  int wm = w >> 1, wn = w & 1;
  for (int kt = 0; kt < 8; kt++){
    #pragma unroll
    for (int i = 0; i < 4; i++){
      gl_lds16(embT + srcA[i] + kt * 64, Ash + (32 * w + 8 * i) * 64);
      gl_lds16(WxT  + srcB[i] + kt * 64, Bsh + (32 * w + 8 * i) * 64);
    }
    __syncthreads();
    #pragma unroll
    for (int kk = 0; kk < 2; kk++){
      short8 a[4], b[4];
      #pragma unroll
      for (int mt = 0; mt < 4; mt++)
        a[mt] = *(const short8*)(Ash + (64 * wm + 16 * mt + (l & 15)) * 64 + kk * 32 + (l >> 4) * 8);
      #pragma unroll
      for (int nt = 0; nt < 4; nt++)
        b[nt] = *(const short8*)(Bsh + (64 * wn + 16 * nt + (l & 15)) * 64 + kk * 32 + (l >> 4) * 8);
      #pragma unroll
      for (int mt = 0; mt < 4; mt++)
        #pragma unroll
        for (int nt = 0; nt < 4; nt++)
          acc[mt][nt] = __builtin_amdgcn_mfma_f32_16x16x32_bf16(a[mt], b[nt], acc[mt][nt], 0, 0, 0);
    }
    __syncthreads();
  }
  #pragma unroll
  for (int mt = 0; mt < 4; mt++)
    #pragma unroll
    for (int nt = 0; nt < 4; nt++)
      #pragma unroll
      for (int r = 0; r < 4; r++){
        int mm = 64 * wm + 16 * mt + 4 * (l >> 4) + r;
        int nn = 64 * wn + 16 * nt + (l & 15);
        float z = acc[mt][nt][r] + biasP[n0 + nn];
        S[mm * 128 + nn] = f2bf(z);
      }
  __syncthreads();
  #pragma unroll
  for (int it = 0; it < 8; it++){
    int i = it * 256 + tid;                 // 0..2047
    int row = i >> 4, ch = i & 15;
    *reinterpret_cast<uint4*>(xz + (long)(m0 + row) * 2048 + n0 + ch * 8) =
        *reinterpret_cast<const uint4*>(S + row * 128 + ch * 8);
  }
}

// ---------------- K3: recurrent LSTM, one time-chunk ----------------
// 64 blocks x 256 thr. 8 groups (16 batch) x 8 members x 4 waves.
// Wave owns dimblk D = member*4+w FULLY (16 dims x 4 gates x K=512):
// 256 AGPRs of stationary W_h pinned via inline asm; no intra-block sync at all.
// Per-pair flags (32/group), all-relaxed agent protocol (proven in R4).
__launch_bounds__(256, 1)
__global__ void k_lstm(const int* __restrict__ seqlen,
                       const unsigned short* __restrict__ WhT,
                       const unsigned short* __restrict__ xz,   // chunk-local [128][CT][2048]
                       unsigned short* __restrict__ hbuf,       // [2][128][512] bf16
                       float* __restrict__ hfin,                // [128][512] f32
                       int* __restrict__ flags,                 // [8 groups][64] ints (32 used)
                       float* __restrict__ cbuf,                // [128][512] f32
                       int lc){
  int bid = blockIdx.x;
  int g = bid & 7, member = bid >> 3;
  int tid = threadIdx.x, w = tid >> 6, l = tid & 63;
  int lm = l & 15, lh = l >> 4;
  int D = member * 4 + w;                  // dimblk 0..31
  int b0 = g * 16;

  int len[4];
  #pragma unroll
  for (int r = 0; r < 4; r++) len[r] = seqlen[b0 + 4 * lh + r];
  int ml = max(max(len[0], len[1]), max(len[2], len[3]));
  #pragma unroll
  for (int off = 32; off; off >>= 1) ml = max(ml, __shfl_xor(ml, off));
  int tstart = lc * CT;
  int tend = min(tstart + CT, ml);
  if (tend <= tstart) return;              // group done in earlier chunk (uniform per block)

  // stationary W_h: 4 gates x 16 k-frags, pinned in 256 AGPRs
  i32x4a Ba[4][16];
  #pragma unroll
  for (int gg = 0; gg < 4; gg++){
    const unsigned short* wb = WhT + (long)(D * 64 + lm * 4 + gg) * 512 + lh * 8;
    #pragma unroll
    for (int kk = 0; kk < 16; kk++)
      Ba[gg][kk] = agpr_load16(wb + kk * 32);
  }
  asm volatile("s_waitcnt vmcnt(0)");

  long cidx[4];
  #pragma unroll
  for (int r = 0; r < 4; r++)
    cidx[r] = (long)(b0 + 4 * lh + r) * 512 + D * 16 + lm;

  float cst[4];
  #pragma unroll
  for (int r = 0; r < 4; r++)
    cst[r] = (lc == 0) ? 0.f : cbuf[cidx[r]];

  long hread_base = (long)(b0 + lm) * 512 + lh * 8;   // + par*65536 + kk*32
  const unsigned long long* hb64 = (const unsigned long long*)hbuf;
  const int* fl = flags + g * 64 + (l & 31);
  f32x4 zero4 = {0.f, 0.f, 0.f, 0.f};

  for (int t = tstart; t < tend; t++){
    int tl = t - tstart;
    // prefetch x-projection values (plain cached loads; independent of h)
    ushort4 xv[4];
    #pragma unroll
    for (int r = 0; r < 4; r++)
      xv[r] = *(const ushort4*)(xz + (long)(b0 + 4 * lh + r) * (CT * N4H)
                                    + (long)tl * N4H + D * 64 + lm * 4);
    f32x4 acc[4] = {zero4, zero4, zero4, zero4};
    if (t > 0){
      // relaxed poll on the group's 32 pair-flags (all lanes; bounded failsafe)
      int spin = 0;
      while (true){
        int f = __hip_atomic_load(fl, __ATOMIC_RELAXED, __HIP_MEMORY_SCOPE_AGENT);
        if (__all(f >= t)) break;
        if (++spin > SPIN_CAP) break;      // failsafe: wrong answer beats dead container
        __builtin_amdgcn_s_sleep(1);
      }
      asm volatile("" ::: "memory");       // pin compiler ordering (sc1 loads; no HW fence)
      long au = (((long)((t - 1) & 1)) * 65536 + hread_base) >> 2;   // ull index
      short8 Af[16];
      #pragma unroll
      for (int kk = 0; kk < 16; kk++){
        unsigned long long lo = __hip_atomic_load(hb64 + au + kk * 8,     __ATOMIC_RELAXED, __HIP_MEMORY_SCOPE_AGENT);
        unsigned long long hi = __hip_atomic_load(hb64 + au + kk * 8 + 1, __ATOMIC_RELAXED, __HIP_MEMORY_SCOPE_AGENT);
        struct P { unsigned long long a, b; } pr{lo, hi};
        Af[kk] = __builtin_bit_cast(short8, pr);
      }
      asm volatile("s_nop 1\n\ts_nop 1");  // VALU->MFMA srcC hazard insurance (inline asm opaque)
      #pragma unroll
      for (int kk = 0; kk < 16; kk++)
        #pragma unroll
        for (int gg = 0; gg < 4; gg++)
          mfma_a(acc[gg], Af[kk], Ba[gg][kk]);
      asm volatile("s_nop 7");             // MFMA->VALU read insurance
    }
    // lane-local gates: lane holds all 4 gates of (b=b0+4*lh+r, dim=D*16+lm)
    float hn[4];
    #pragma unroll
    for (int r = 0; r < 4; r++){
      float zf = acc[0][r] + bf2f(xv[r].x);
      float zi = acc[1][r] + bf2f(xv[r].y);
      float zo = acc[2][r] + bf2f(xv[r].z);
      float zc = acc[3][r] + bf2f(xv[r].w);
      float fg = sigm_(zf), ig = sigm_(zi), og = sigm_(zo);
      float ch = tanh_(zc);
      float cn = fg * cst[r] + ig * ch;
      cst[r] = cn;
      hn[r] = og * tanh_(cn);
      int b = b0 + 4 * lh + r;
      __hip_atomic_store(&hbuf[(long)(t & 1) * 65536 + (long)b * 512 + D * 16 + lm],
                         f2bf(hn[r]), __ATOMIC_RELAXED, __HIP_MEMORY_SCOPE_AGENT);
    }
    // drain this wave's h stores to the coherent point, then publish flag (relaxed)
    asm volatile("s_waitcnt vmcnt(0)" ::: "memory");
    if (l == 0)
      __hip_atomic_store(&flags[g * 64 + member * 4 + w], t + 1,
                         __ATOMIC_RELAXED, __HIP_MEMORY_SCOPE_AGENT);
    // hfin off the critical path (after flag publish)
    #pragma unroll
    for (int r = 0; r < 4; r++)
      if (t == len[r] - 1) hfin[cidx[r]] = hn[r];
  }
  #pragma unroll
  for (int r = 0; r < 4; r++) cbuf[cidx[r]] = cst[r];
}

// ---------------- K4: final FC [128,512]@[512,5] fp32 ----------------
__global__ void k_fc(const float* __restrict__ hfin, const float* __restrict__ fcw,
                     const float* __restrict__ fcb, float* __restrict__ out){
  int b = blockIdx.x;
  int l = threadIdx.x;                     // 64 threads = 1 wave
  const float* h = hfin + (long)b * 512;
  float a[5] = {0.f, 0.f, 0.f, 0.f, 0.f};
  for (int k = l; k < 512; k += 64){
    float hv = h[k];
    #pragma unroll
    for (int o = 0; o < 5; o++) a[o] += hv * fcw[k * 5 + o];
  }
  #pragma unroll
  for (int o = 0; o < 5; o++){
    float v = a[o];
    #pragma unroll
    for (int off = 32; off; off >>= 1) v += __shfl_xor(v, off);
    if (l == 0) out[b * 5 + o] = v + fcb[o];
  }
}

extern "C" void kernel_launch(void* const* d_in, const int* in_sizes, int n_in,
                              void* d_out, int out_size, void* d_ws, size_t ws_size,
                              hipStream_t stream) {
  const int*   inputs = (const int*)  d_in[0];
  const int*   seqlen = (const int*)  d_in[1];
  const float* embed  = (const float*)d_in[2];
  const float* wf  = (const float*)d_in[3];
  const float* bfp = (const float*)d_in[4];
  const float* wi  = (const float*)d_in[5];
  const float* bip = (const float*)d_in[6];
  const float* wo  = (const float*)d_in[7];
  const float* bop = (const float*)d_in[8];
  const float* wc  = (const float*)d_in[9];
  const float* bcp = (const float*)d_in[10];
  const float* fcw = (const float*)d_in[11];
  const float* fcb = (const float*)d_in[12];
  float* out = (float*)d_out;

  // workspace layout (bytes)
  size_t SZ_XZ   = (size_t)NB * CT * N4H * 2;      // 64 MB (one time-chunk)
  size_t SZ_EMBT = (size_t)NV * NE * 2;            // 31.25 MB
  size_t SZ_W    = (size_t)N4H * 512 * 2;          // 2 MB
  size_t SZ_BIAS = (size_t)N4H * 4;                // 8 KB
  size_t SZ_HBUF = (size_t)2 * NB * NH * 2;        // 256 KB
  size_t SZ_F32B = (size_t)NB * NH * 4;            // 256 KB (cbuf / hfin)
  size_t SZ_FLAG = 4096;
  size_t need = SZ_XZ + SZ_EMBT + 2 * SZ_W + SZ_BIAS + SZ_HBUF + 2 * SZ_F32B + SZ_FLAG;
  if (ws_size < need){
    hipMemsetAsync(d_out, 0, (size_t)out_size * 4, stream);   // diagnostic signature
    return;
  }

  char* ws = (char*)d_ws;
  unsigned short* xz    = (unsigned short*)(ws);
  unsigned short* embT  = (unsigned short*)(ws + SZ_XZ);
  unsigned short* WxT   = (unsigned short*)(ws + SZ_XZ + SZ_EMBT);
  unsigned short* WhT   = (unsigned short*)(ws + SZ_XZ + SZ_EMBT + SZ_W);
  float*          biasP = (float*)        (ws + SZ_XZ + SZ_EMBT + 2 * SZ_W);
  unsigned short* hbuf  = (unsigned short*)(ws + SZ_XZ + SZ_EMBT + 2 * SZ_W + SZ_BIAS);
  float*          cbuf  = (float*)        (ws + SZ_XZ + SZ_EMBT + 2 * SZ_W + SZ_BIAS + SZ_HBUF);
  float*          hfin  = (float*)        (ws + SZ_XZ + SZ_EMBT + 2 * SZ_W + SZ_BIAS + SZ_HBUF + SZ_F32B);
  int*            flags = (int*)          (ws + SZ_XZ + SZ_EMBT + 2 * SZ_W + SZ_BIAS + SZ_HBUF + 2 * SZ_F32B);

  hipMemsetAsync(flags, 0, SZ_FLAG, stream);
  k_cvt_embed<<<2048, 256, 0, stream>>>(embed, embT, (long)NV * NE);
  k_prep_w<<<2048, 256, 0, stream>>>(wf, wi, wo, wc, bfp, bip, bop, bcp, WhT, WxT, biasP);

  for (int c = 0; c < NCHUNK; c++){
    k_xproj<<<2048, 256, 0, stream>>>(inputs, embT, WxT, biasP, xz, c);
    k_lstm<<<64, 256, 0, stream>>>(seqlen, WhT, xz, hbuf, hfin, flags, cbuf, c);
  }
  k_fc<<<128, 64, 0, stream>>>(hfin, fcw, fcb, out);
}